// Round 1
// baseline (582.019 us; speedup 1.0000x reference)
//
#include <hip/hip_runtime.h>
#include <cstdint>
#include <cstddef>

typedef __attribute__((ext_vector_type(4))) float v4f;
typedef __attribute__((ext_vector_type(8))) short v8s;

__device__ __forceinline__ short f2bf(float f) {
  unsigned u = __float_as_uint(f);
  u += 0x7FFFu + ((u >> 16) & 1u);   // round-to-nearest-even
  return (short)(u >> 16);
}
__device__ __forceinline__ float bf2f(short h) {
  return __uint_as_float(((unsigned)(unsigned short)h) << 16);
}
__device__ __forceinline__ v4f mfma16(v8s a, v8s b, v4f c) {
  return __builtin_amdgcn_mfma_f32_16x16x32_bf16(a, b, c, 0, 0, 0);
}

// ---------------- workspace layout (bytes) ----------------
#define OFF_GRAM   0u          // double[2*8*16*16] = 32768
#define OFF_QN     32768u      // double[256]
#define OFF_KN     34816u      // double[256]
#define OFF_GSUM   36864u      // double[1]
#define OFF_ATTN   40960u      // float[4096]
#define OFF_WQH    65536u      // short[384*128]
#define OFF_WQL    163840u
#define OFF_G1H    262144u     // short[128*256]
#define OFF_G1L    327680u
#define OFF_W2     393216u     // short[2*256*256]
#define OFF_QKV    1048576u    // float[131072*384] pixel-major
#define OFF_V      202375168u  // short[131072*128] pixel-major bf16
// total needed ~225 MiB

// K0: split fp32 weights into bf16 hi/lo planes (for fp32-accurate split MFMA)
__global__ void k0_split(const float* __restrict__ qkv_w, const float* __restrict__ g1_w,
                         short* __restrict__ wqh, short* __restrict__ wql,
                         short* __restrict__ g1h, short* __restrict__ g1l) {
  int i = blockIdx.x * 256 + threadIdx.x;
  if (i < 49152) {
    float f = qkv_w[i]; short h = f2bf(f);
    wqh[i] = h; wql[i] = f2bf(f - bf2f(h));
  }
  int j = i - 49152;
  if (j >= 0 && j < 32768) {
    float f = g1_w[j]; short h = f2bf(f);
    g1h[j] = h; g1l[j] = f2bf(f - bf2f(h));
  }
}

// K1: qkv = x1 @ Wqkv^T  (M=131072, K=128, N=384), split-bf16 (4-term), fp32 out pixel-major
__global__ __launch_bounds__(512) void k1_qkv(const float* __restrict__ x,
                                              const short* __restrict__ wqh,
                                              const short* __restrict__ wql,
                                              float* __restrict__ qkv) {
  __shared__ __align__(16) unsigned char sm[65536]; // Ah@0 Al@16384 Bh@32768 Bl@49152, [64][128] bf16 swz
  const int tid = threadIdx.x;
  const size_t m0 = (size_t)blockIdx.x * 64;
  { // stage A = x rows, cols 0..127, converted to hi/lo bf16
    const int row = tid >> 3, c0 = (tid & 7) * 16;
    const float* src = x + (m0 + (size_t)row) * 256 + c0;
#pragma unroll
    for (int half = 0; half < 2; ++half) {
      v4f f0 = *(const v4f*)(src + half * 8);
      v4f f1 = *(const v4f*)(src + half * 8 + 4);
      v8s hi, lo;
#pragma unroll
      for (int j = 0; j < 4; ++j) {
        short h0 = f2bf(f0[j]); hi[j] = h0;   lo[j]   = f2bf(f0[j] - bf2f(h0));
        short h1 = f2bf(f1[j]); hi[4+j] = h1; lo[4+j] = f2bf(f1[j] - bf2f(h1));
      }
      const int col = c0 + half * 8;
      const int byo = (row * 256 + col * 2) ^ ((row & 7) << 4);
      *(v8s*)(sm + byo) = hi;
      *(v8s*)(sm + 16384 + byo) = lo;
    }
  }
  const int lane = tid & 63, wid = tid >> 6;
  const int wm = wid >> 2, wn = wid & 3; // 2(m) x 4(n) waves, wave tile 32x16
  const v4f vz = {0.f, 0.f, 0.f, 0.f};
  v4f acc[6][2];
#pragma unroll
  for (int i = 0; i < 6; ++i) { acc[i][0] = vz; acc[i][1] = vz; }
#pragma unroll
  for (int nc = 0; nc < 6; ++nc) {
    __syncthreads();
    { // stage B chunk: weight rows nc*64..+64 (layout [n][k], k contiguous)
      const int row = tid >> 3, c0 = (tid & 7) * 16;
      const short* srch = wqh + (size_t)(nc * 64 + row) * 128 + c0;
      const short* srcl = wql + (size_t)(nc * 64 + row) * 128 + c0;
#pragma unroll
      for (int half = 0; half < 2; ++half) {
        const int col = c0 + half * 8;
        const int byo = (row * 256 + col * 2) ^ ((row & 7) << 4);
        *(v8s*)(sm + 32768 + byo) = *(const v8s*)(srch + half * 8);
        *(v8s*)(sm + 49152 + byo) = *(const v8s*)(srcl + half * 8);
      }
    }
    __syncthreads();
#pragma unroll
    for (int ks = 0; ks < 4; ++ks) {
      const int kb2 = (ks * 32 + ((lane >> 4) * 8)) * 2;
      const int n = wn * 16 + (lane & 15);
      const int byoB = (n * 256 + kb2) ^ ((n & 7) << 4);
      v8s bh = *(const v8s*)(sm + 32768 + byoB);
      v8s bl = *(const v8s*)(sm + 49152 + byoB);
#pragma unroll
      for (int mi = 0; mi < 2; ++mi) {
        const int m = wm * 32 + mi * 16 + (lane & 15);
        const int byoA = (m * 256 + kb2) ^ ((m & 7) << 4);
        v8s ah = *(const v8s*)(sm + byoA);
        v8s al = *(const v8s*)(sm + 16384 + byoA);
        acc[nc][mi] = mfma16(ah, bh, acc[nc][mi]);
        acc[nc][mi] = mfma16(al, bh, acc[nc][mi]);
        acc[nc][mi] = mfma16(ah, bl, acc[nc][mi]);
        acc[nc][mi] = mfma16(al, bl, acc[nc][mi]);
      }
    }
  }
#pragma unroll
  for (int nc = 0; nc < 6; ++nc)
#pragma unroll
    for (int mi = 0; mi < 2; ++mi)
#pragma unroll
      for (int r = 0; r < 4; ++r) {
        const int m = wm * 32 + mi * 16 + ((lane >> 4) * 4) + r;
        const int n = nc * 64 + wn * 16 + (lane & 15);
        qkv[(m0 + m) * 384 + n] = acc[nc][mi][r];
      }
}

// K1g: g1 = x @ W1^T (K=256,N=128) split-bf16, fused relu+g2 dot+sigmoid+global mean (double atomic)
__global__ __launch_bounds__(512) void k1_g(const float* __restrict__ x,
                                            const short* __restrict__ g1h,
                                            const short* __restrict__ g1l,
                                            const float* __restrict__ g1_b,
                                            const float* __restrict__ g2_w,
                                            const float* __restrict__ g2_b,
                                            double* __restrict__ gsum) {
  __shared__ __align__(16) unsigned char sm[65536];
  const int tid = threadIdx.x;
  const size_t m0 = (size_t)blockIdx.x * 64;
  const int lane = tid & 63, wid = tid >> 6;
  const int wm = wid >> 2, wn = wid & 3;
  const v4f vz = {0.f, 0.f, 0.f, 0.f};
  v4f acc[2][2];
  acc[0][0] = vz; acc[0][1] = vz; acc[1][0] = vz; acc[1][1] = vz;
#pragma unroll
  for (int kc = 0; kc < 2; ++kc) {
    __syncthreads();
    { // stage A chunk (cols kc*128..+128)
      const int row = tid >> 3, c0 = (tid & 7) * 16;
      const float* src = x + (m0 + (size_t)row) * 256 + kc * 128 + c0;
#pragma unroll
      for (int half = 0; half < 2; ++half) {
        v4f f0 = *(const v4f*)(src + half * 8);
        v4f f1 = *(const v4f*)(src + half * 8 + 4);
        v8s hi, lo;
#pragma unroll
        for (int j = 0; j < 4; ++j) {
          short h0 = f2bf(f0[j]); hi[j] = h0;   lo[j]   = f2bf(f0[j] - bf2f(h0));
          short h1 = f2bf(f1[j]); hi[4+j] = h1; lo[4+j] = f2bf(f1[j] - bf2f(h1));
        }
        const int col = c0 + half * 8;
        const int byo = (row * 256 + col * 2) ^ ((row & 7) << 4);
        *(v8s*)(sm + byo) = hi;
        *(v8s*)(sm + 16384 + byo) = lo;
      }
    }
#pragma unroll
    for (int nc = 0; nc < 2; ++nc) {
      __syncthreads();
      {
        const int row = tid >> 3, c0 = (tid & 7) * 16;
        const short* srch = g1h + (size_t)(nc * 64 + row) * 256 + kc * 128 + c0;
        const short* srcl = g1l + (size_t)(nc * 64 + row) * 256 + kc * 128 + c0;
#pragma unroll
        for (int half = 0; half < 2; ++half) {
          const int col = c0 + half * 8;
          const int byo = (row * 256 + col * 2) ^ ((row & 7) << 4);
          *(v8s*)(sm + 32768 + byo) = *(const v8s*)(srch + half * 8);
          *(v8s*)(sm + 49152 + byo) = *(const v8s*)(srcl + half * 8);
        }
      }
      __syncthreads();
#pragma unroll
      for (int ks = 0; ks < 4; ++ks) {
        const int kb2 = (ks * 32 + ((lane >> 4) * 8)) * 2;
        const int n = wn * 16 + (lane & 15);
        const int byoB = (n * 256 + kb2) ^ ((n & 7) << 4);
        v8s bh = *(const v8s*)(sm + 32768 + byoB);
        v8s bl = *(const v8s*)(sm + 49152 + byoB);
#pragma unroll
        for (int mi = 0; mi < 2; ++mi) {
          const int m = wm * 32 + mi * 16 + (lane & 15);
          const int byoA = (m * 256 + kb2) ^ ((m & 7) << 4);
          v8s ah = *(const v8s*)(sm + byoA);
          v8s al = *(const v8s*)(sm + 16384 + byoA);
          acc[nc][mi] = mfma16(ah, bh, acc[nc][mi]);
          acc[nc][mi] = mfma16(al, bh, acc[nc][mi]);
          acc[nc][mi] = mfma16(ah, bl, acc[nc][mi]);
          acc[nc][mi] = mfma16(al, bl, acc[nc][mi]);
        }
      }
    }
  }
  // epilogue: per-pixel g2 dot + sigmoid + block sum -> double atomic
  __syncthreads();
  float* g2ws = (float*)sm;           // aliases dead A region
  float* ldsg = (float*)(sm + 512);
  if (tid < 128) g2ws[tid] = g2_w[tid];
  if (tid < 64) ldsg[tid] = 0.f;
  __syncthreads();
  float bias[2], g2v[2];
#pragma unroll
  for (int nc = 0; nc < 2; ++nc) {
    const int n = nc * 64 + wn * 16 + (lane & 15);
    bias[nc] = g1_b[n];
    g2v[nc] = g2ws[n];
  }
#pragma unroll
  for (int mi = 0; mi < 2; ++mi)
#pragma unroll
    for (int r = 0; r < 4; ++r) {
      float part = 0.f;
#pragma unroll
      for (int nc = 0; nc < 2; ++nc) {
        float val = acc[nc][mi][r] + bias[nc];
        val = fmaxf(val, 0.f);
        part += val * g2v[nc];
      }
      part += __shfl_xor(part, 1, 16);
      part += __shfl_xor(part, 2, 16);
      part += __shfl_xor(part, 4, 16);
      part += __shfl_xor(part, 8, 16);
      if ((lane & 15) == 0)
        atomicAdd(&ldsg[wm * 32 + mi * 16 + ((lane >> 4) * 4) + r], part);
    }
  __syncthreads();
  if (tid < 64) {
    float pre = ldsg[tid] + g2_b[0];
    float g = 1.f / (1.f + expf(-pre));
#pragma unroll
    for (int mk = 1; mk < 64; mk <<= 1) g += __shfl_xor(g, mk, 64);
    if (tid == 0) atomicAdd(gsum, (double)g);
  }
}

// K2: fused 3x3 depthwise conv + channel norms + 16x16 gram (split-bf16 MFMA) + v write (bf16)
// grid (256 tiles, 8 heads, 2 batch), block 256 (16x16 pixel tile, 1 px/thread)
__global__ __launch_bounds__(256) void k2_conv(const float* __restrict__ qkv,
                                               const float* __restrict__ dw_w,
                                               double* __restrict__ gram,
                                               double* __restrict__ qn,
                                               double* __restrict__ kn,
                                               short* __restrict__ vbuf) {
  __shared__ float halo[324 * 21];   // [18*18 pos][16 ch] stride 21 (bank-friendly)
  __shared__ float qld[16 * 260];    // [c][pixel] fp32
  __shared__ float kld[16 * 260];
  __shared__ float wsm[144];
  __shared__ float ldsG[256];
  const int tid = threadIdx.x;
  const int tile = blockIdx.x, h = blockIdx.y, b = blockIdx.z;
  const int px0 = (tile & 15) * 16, py0 = (tile >> 4) * 16;
  const int tx = tid & 15, ty = tid >> 4;
  const int lane = tid & 63, w4 = tid >> 6;

  auto stage = [&](int sec) {
    const int chbase = sec * 128 + h * 16;
    for (int idx = tid; idx < 5184; idx += 256) {
      const int p = idx >> 4, cc = idx & 15;
      const int row = p / 18, col = p - row * 18;
      const int gy = py0 - 1 + row, gx = px0 - 1 + col;
      float v = 0.f;
      if (gy >= 0 && gy < 256 && gx >= 0 && gx < 256)
        v = qkv[((size_t)b * 65536 + (size_t)gy * 256 + gx) * 384 + chbase + cc];
      halo[p * 21 + cc] = v;
    }
    if (tid < 144) wsm[tid] = dw_w[(chbase + tid / 9) * 9 + tid % 9];
  };
  auto conv16 = [&](float* o) {
#pragma unroll
    for (int cc = 0; cc < 16; ++cc) {
      float s = 0.f;
#pragma unroll
      for (int dy = 0; dy < 3; ++dy)
#pragma unroll
        for (int dx = 0; dx < 3; ++dx)
          s += wsm[cc * 9 + dy * 3 + dx] * halo[((ty + dy) * 18 + tx + dx) * 21 + cc];
      o[cc] = s;
    }
  };

  float tmp[16];
  stage(0);
  __syncthreads();
  conv16(tmp);
#pragma unroll
  for (int cc = 0; cc < 16; ++cc) qld[cc * 260 + tid] = tmp[cc];
  __syncthreads();
  stage(1);
  __syncthreads();
  conv16(tmp);
#pragma unroll
  for (int cc = 0; cc < 16; ++cc) kld[cc * 260 + tid] = tmp[cc];
  ldsG[tid] = 0.f;
  __syncthreads();
  // overlap: v-halo staging + norms + gram (none touch each other's buffers)
  stage(2);
  { // channel L2-norm partials (per block) -> double atomics
    const int cc = tid >> 4, j0 = tid & 15;
    float s = 0.f;
#pragma unroll
    for (int j = 0; j < 16; ++j) { const float v = qld[cc * 260 + j0 + j * 16]; s += v * v; }
    s += __shfl_xor(s, 1, 16); s += __shfl_xor(s, 2, 16);
    s += __shfl_xor(s, 4, 16); s += __shfl_xor(s, 8, 16);
    if (j0 == 0) atomicAdd(&qn[b * 128 + h * 16 + cc], (double)s);
    s = 0.f;
#pragma unroll
    for (int j = 0; j < 16; ++j) { const float v = kld[cc * 260 + j0 + j * 16]; s += v * v; }
    s += __shfl_xor(s, 1, 16); s += __shfl_xor(s, 2, 16);
    s += __shfl_xor(s, 4, 16); s += __shfl_xor(s, 8, 16);
    if (j0 == 0) atomicAdd(&kn[b * 128 + h * 16 + cc], (double)s);
  }
  { // gram partial: G[c][d] += sum_px q_c * k_d  via split-bf16 MFMA (K=64 per wave)
    v4f acc = {0.f, 0.f, 0.f, 0.f};
#pragma unroll
    for (int s2 = 0; s2 < 2; ++s2) {
      const int pb = w4 * 64 + s2 * 32 + ((lane >> 4) * 8);
      const float* qp = &qld[(lane & 15) * 260 + pb];
      const float* kp = &kld[(lane & 15) * 260 + pb];
      v8s qh, ql2, kh, kl2;
#pragma unroll
      for (int e = 0; e < 8; ++e) {
        const float qv2 = qp[e]; const short hq = f2bf(qv2);
        qh[e] = hq; ql2[e] = f2bf(qv2 - bf2f(hq));
        const float kv2 = kp[e]; const short hk = f2bf(kv2);
        kh[e] = hk; kl2[e] = f2bf(kv2 - bf2f(hk));
      }
      acc = mfma16(qh, kh, acc);
      acc = mfma16(ql2, kh, acc);
      acc = mfma16(qh, kl2, acc);
      acc = mfma16(ql2, kl2, acc);
    }
#pragma unroll
    for (int r = 0; r < 4; ++r)
      atomicAdd(&ldsG[((lane >> 4) * 4 + r) * 16 + (lane & 15)], acc[r]);
  }
  __syncthreads();
  conv16(tmp);
  { // write v bf16, pixel-major [m][128]
    v8s o0, o1;
#pragma unroll
    for (int j = 0; j < 8; ++j) { o0[j] = f2bf(tmp[j]); o1[j] = f2bf(tmp[8 + j]); }
    short* dst = vbuf + ((size_t)b * 65536 + (size_t)(py0 + ty) * 256 + (px0 + tx)) * 128 + h * 16;
    *(v8s*)dst = o0;
    *(v8s*)(dst + 8) = o1;
  }
  atomicAdd(&gram[(size_t)(b * 8 + h) * 256 + tid], (double)ldsG[tid]);
}

// K3a: normalize gram -> cosine attn, temperature, dyn_k top-k mask, softmax, *sum(attn1..4)
__global__ void k3a_attn(const double* __restrict__ gram, const double* __restrict__ qn,
                         const double* __restrict__ kn, const double* __restrict__ gsum,
                         const float* __restrict__ temp,
                         const float* __restrict__ a1p, const float* __restrict__ a2p,
                         const float* __restrict__ a3p, const float* __restrict__ a4p,
                         float* __restrict__ attnw) {
  const int t = threadIdx.x;  // 256 rows: (b,h,c)
  const int b = t >> 7, rem = t & 127, h = rem >> 4, c = rem & 15;
  const float qnv = fmaxf(sqrtf((float)qn[b * 128 + h * 16 + c]), 1e-12f);
  const float tv = temp[h];
  float a[16];
#pragma unroll
  for (int d = 0; d < 16; ++d) {
    const float knv = fmaxf(sqrtf((float)kn[b * 128 + h * 16 + d]), 1e-12f);
    a[d] = (float)gram[(size_t)(b * 8 + h) * 256 + c * 16 + d] / (qnv * knv) * tv;
  }
  const float dynk = floorf(16.f * (float)(gsum[0] / 131072.0));
  float mx = -INFINITY;
  bool keep[16];
#pragma unroll
  for (int d = 0; d < 16; ++d) {
    int rank = 0;
#pragma unroll
    for (int e = 0; e < 16; ++e)
      rank += ((a[e] > a[d]) || ((a[e] == a[d]) && (e < d))) ? 1 : 0;
    keep[d] = ((float)rank < dynk);
    if (keep[d]) mx = fmaxf(mx, a[d]);
  }
  float ssum = 0.f, wvv[16];
#pragma unroll
  for (int d = 0; d < 16; ++d) {
    wvv[d] = keep[d] ? expf(a[d] - mx) : 0.f;
    ssum += wvv[d];
  }
  const float satt = a1p[0] + a2p[0] + a3p[0] + a4p[0];
  const float sc = satt / ssum;
#pragma unroll
  for (int d = 0; d < 16; ++d) attnw[t * 16 + d] = wvv[d] * sc;
}

// K3b: fold attention into projection: W2[b][o][c'] (bf16)
__global__ void k3b_fold(const float* __restrict__ proj_w, const float* __restrict__ attnw,
                         short* __restrict__ W2) {
  const int o = blockIdx.x, b = blockIdx.y, cp = threadIdx.x;  // 256 threads
  float val;
  if (cp < 128) {
    const int h = cp >> 4, d = cp & 15;
    float s = 0.f;
#pragma unroll
    for (int i = 0; i < 16; ++i)
      s += proj_w[o * 256 + h * 16 + i] * attnw[((b * 8 + h) * 16 + i) * 16 + d];
    val = s;
  } else {
    val = proj_w[o * 256 + cp];
  }
  W2[(size_t)(b * 256 + o) * 256 + cp] = f2bf(val);
}

// K4: out[m][o] = [v(m) ; x2(m)] @ W2[b]^T   (M=131072, K=256, N=256) plain bf16 MFMA
__global__ __launch_bounds__(512) void k4_out(const short* __restrict__ vbuf,
                                              const float* __restrict__ x,
                                              const short* __restrict__ W2,
                                              float* __restrict__ out) {
  __shared__ __align__(16) unsigned char sm[65536]; // A [64][256] bf16 @0, B [64][256] bf16 @32768
  const int tid = threadIdx.x;
  const size_t m0 = (size_t)blockIdx.x * 64;
  const int b = (int)(m0 >> 16);
  {
    const int row = tid >> 3, c0 = (tid & 7) * 16;
    { // cols 0..127 from v (already bf16)
      const short* src = vbuf + (m0 + (size_t)row) * 128 + c0;
#pragma unroll
      for (int half = 0; half < 2; ++half) {
        const int col = c0 + half * 8;
        const int byo = (row * 512 + col * 2) ^ ((row & 7) << 4);
        *(v8s*)(sm + byo) = *(const v8s*)(src + half * 8);
      }
    }
    { // cols 128..255 from x2 (fp32 -> bf16)
      const float* src = x + (m0 + (size_t)row) * 256 + 128 + c0;
#pragma unroll
      for (int half = 0; half < 2; ++half) {
        v4f f0 = *(const v4f*)(src + half * 8);
        v4f f1 = *(const v4f*)(src + half * 8 + 4);
        v8s hv;
#pragma unroll
        for (int j = 0; j < 4; ++j) { hv[j] = f2bf(f0[j]); hv[4+j] = f2bf(f1[j]); }
        const int col = 128 + c0 + half * 8;
        const int byo = (row * 512 + col * 2) ^ ((row & 7) << 4);
        *(v8s*)(sm + byo) = hv;
      }
    }
  }
  const int lane = tid & 63, wid = tid >> 6;
  const int wm = wid >> 2, wn = wid & 3;
  for (int nc = 0; nc < 4; ++nc) {
    __syncthreads();
    { // stage B rows nc*64..+64 of W2[b]
      const int row = tid >> 3, c0 = (tid & 7) * 32;
      const short* src = W2 + ((size_t)(b * 256 + nc * 64 + row)) * 256 + c0;
#pragma unroll
      for (int q = 0; q < 4; ++q) {
        const int col = c0 + q * 8;
        const int byo = (row * 512 + col * 2) ^ ((row & 7) << 4);
        *(v8s*)(sm + 32768 + byo) = *(const v8s*)(src + q * 8);
      }
    }
    __syncthreads();
    v4f acc[2] = {{0.f,0.f,0.f,0.f},{0.f,0.f,0.f,0.f}};
#pragma unroll
    for (int ks = 0; ks < 8; ++ks) {
      const int kb2 = (ks * 32 + ((lane >> 4) * 8)) * 2;
      const int n = wn * 16 + (lane & 15);
      const int byoB = (n * 512 + kb2) ^ ((n & 7) << 4);
      const v8s bf = *(const v8s*)(sm + 32768 + byoB);
#pragma unroll
      for (int mi = 0; mi < 2; ++mi) {
        const int m = wm * 32 + mi * 16 + (lane & 15);
        const int byoA = (m * 512 + kb2) ^ ((m & 7) << 4);
        const v8s af = *(const v8s*)(sm + byoA);
        acc[mi] = mfma16(af, bf, acc[mi]);
      }
    }
#pragma unroll
    for (int mi = 0; mi < 2; ++mi)
#pragma unroll
      for (int r = 0; r < 4; ++r) {
        const int m = wm * 32 + mi * 16 + ((lane >> 4) * 4) + r;
        const int o = nc * 64 + wn * 16 + (lane & 15);
        out[(m0 + m) * 256 + o] = acc[mi][r];
      }
  }
}

extern "C" void kernel_launch(void* const* d_in, const int* in_sizes, int n_in,
                              void* d_out, int out_size, void* d_ws, size_t ws_size,
                              hipStream_t stream) {
  const float* x      = (const float*)d_in[0];
  const float* qkv_w  = (const float*)d_in[1];
  const float* dw_w   = (const float*)d_in[2];
  const float* proj_w = (const float*)d_in[3];
  const float* g1_w   = (const float*)d_in[4];
  const float* g1_b   = (const float*)d_in[5];
  const float* g2_w   = (const float*)d_in[6];
  const float* g2_b   = (const float*)d_in[7];
  const float* temp   = (const float*)d_in[8];
  const float* a1     = (const float*)d_in[9];
  const float* a2     = (const float*)d_in[10];
  const float* a3     = (const float*)d_in[11];
  const float* a4     = (const float*)d_in[12];
  float* out = (float*)d_out;
  char* ws = (char*)d_ws;

  double* gram  = (double*)(ws + OFF_GRAM);
  double* qn    = (double*)(ws + OFF_QN);
  double* kn    = (double*)(ws + OFF_KN);
  double* gsum  = (double*)(ws + OFF_GSUM);
  float*  attnw = (float*)(ws + OFF_ATTN);
  short*  wqh   = (short*)(ws + OFF_WQH);
  short*  wql   = (short*)(ws + OFF_WQL);
  short*  g1h   = (short*)(ws + OFF_G1H);
  short*  g1l   = (short*)(ws + OFF_G1L);
  short*  W2    = (short*)(ws + OFF_W2);
  float*  qkv   = (float*)(ws + OFF_QKV);
  short*  vbuf  = (short*)(ws + OFF_V);

  hipMemsetAsync(ws, 0, 40960, stream);                       // gram/qn/kn/gsum accumulators
  k0_split<<<320, 256, 0, stream>>>(qkv_w, g1_w, wqh, wql, g1h, g1l);
  k1_qkv<<<2048, 512, 0, stream>>>(x, wqh, wql, qkv);
  k1_g<<<2048, 512, 0, stream>>>(x, g1h, g1l, g1_b, g2_w, g2_b, gsum);
  k2_conv<<<dim3(256, 8, 2), 256, 0, stream>>>(qkv, dw_w, gram, qn, kn, vbuf);
  k3a_attn<<<1, 256, 0, stream>>>(gram, qn, kn, gsum, temp, a1, a2, a3, a4, attnw);
  k3b_fold<<<dim3(256, 2), 256, 0, stream>>>(proj_w, attnw, W2);
  k4_out<<<2048, 512, 0, stream>>>(vbuf, x, W2, out);
  (void)in_sizes; (void)n_in; (void)out_size; (void)ws_size;
}

// Round 2
// 340.345 us; speedup vs baseline: 1.7101x; 1.7101x over previous
//
#include <hip/hip_runtime.h>
#include <cstdint>
#include <cstddef>

typedef __attribute__((ext_vector_type(4))) float v4f;
typedef __attribute__((ext_vector_type(8))) short v8s;

__device__ __forceinline__ short f2bf(float f) {
  unsigned u = __float_as_uint(f);
  u += 0x7FFFu + ((u >> 16) & 1u);   // round-to-nearest-even
  return (short)(u >> 16);
}
__device__ __forceinline__ float bf2f(short h) {
  return __uint_as_float(((unsigned)(unsigned short)h) << 16);
}
__device__ __forceinline__ v4f mfma16(v8s a, v8s b, v4f c) {
  return __builtin_amdgcn_mfma_f32_16x16x32_bf16(a, b, c, 0, 0, 0);
}

// ---------------- workspace layout (bytes) ----------------
#define OFF_GRAM   0u          // double[2*8*16*16] = 32768
#define OFF_QN     32768u      // double[256]
#define OFF_KN     34816u      // double[256]
#define OFF_GSUM   36864u      // double[1]
#define OFF_ATTN   40960u      // float[4096]
#define OFF_WQH    65536u      // short[384*128]
#define OFF_WQL    163840u
#define OFF_G1H    262144u     // short[128*256]
#define OFF_G1L    327680u
#define OFF_W2     393216u     // short[2*256*256]
#define OFF_QKV    1048576u    // float[131072*384] pixel-major
#define OFF_V      202375168u  // short[131072*128] pixel-major bf16
// total needed ~225 MiB

// K0: split fp32 weights into bf16 hi/lo planes (for fp32-accurate split MFMA)
__global__ void k0_split(const float* __restrict__ qkv_w, const float* __restrict__ g1_w,
                         short* __restrict__ wqh, short* __restrict__ wql,
                         short* __restrict__ g1h, short* __restrict__ g1l) {
  int i = blockIdx.x * 256 + threadIdx.x;
  if (i < 49152) {
    float f = qkv_w[i]; short h = f2bf(f);
    wqh[i] = h; wql[i] = f2bf(f - bf2f(h));
  }
  int j = i - 49152;
  if (j >= 0 && j < 32768) {
    float f = g1_w[j]; short h = f2bf(f);
    g1h[j] = h; g1l[j] = f2bf(f - bf2f(h));
  }
}

// K1: qkv = x1 @ Wqkv^T  (M=131072, K=128, N=384), split-bf16 (4-term), fp32 out pixel-major
__global__ __launch_bounds__(512) void k1_qkv(const float* __restrict__ x,
                                              const short* __restrict__ wqh,
                                              const short* __restrict__ wql,
                                              float* __restrict__ qkv) {
  __shared__ __align__(16) unsigned char sm[65536]; // Ah@0 Al@16384 Bh@32768 Bl@49152, [64][128] bf16 swz
  const int tid = threadIdx.x;
  const size_t m0 = (size_t)blockIdx.x * 64;
  { // stage A = x rows, cols 0..127, converted to hi/lo bf16
    const int row = tid >> 3, c0 = (tid & 7) * 16;
    const float* src = x + (m0 + (size_t)row) * 256 + c0;
#pragma unroll
    for (int half = 0; half < 2; ++half) {
      v4f f0 = *(const v4f*)(src + half * 8);
      v4f f1 = *(const v4f*)(src + half * 8 + 4);
      v8s hi, lo;
#pragma unroll
      for (int j = 0; j < 4; ++j) {
        short h0 = f2bf(f0[j]); hi[j] = h0;   lo[j]   = f2bf(f0[j] - bf2f(h0));
        short h1 = f2bf(f1[j]); hi[4+j] = h1; lo[4+j] = f2bf(f1[j] - bf2f(h1));
      }
      const int col = c0 + half * 8;
      const int byo = (row * 256 + col * 2) ^ ((row & 7) << 4);
      *(v8s*)(sm + byo) = hi;
      *(v8s*)(sm + 16384 + byo) = lo;
    }
  }
  const int lane = tid & 63, wid = tid >> 6;
  const int wm = wid >> 2, wn = wid & 3; // 2(m) x 4(n) waves, wave tile 32x16
  const v4f vz = {0.f, 0.f, 0.f, 0.f};
  v4f acc[6][2];
#pragma unroll
  for (int i = 0; i < 6; ++i) { acc[i][0] = vz; acc[i][1] = vz; }
#pragma unroll
  for (int nc = 0; nc < 6; ++nc) {
    __syncthreads();
    { // stage B chunk: weight rows nc*64..+64 (layout [n][k], k contiguous)
      const int row = tid >> 3, c0 = (tid & 7) * 16;
      const short* srch = wqh + (size_t)(nc * 64 + row) * 128 + c0;
      const short* srcl = wql + (size_t)(nc * 64 + row) * 128 + c0;
#pragma unroll
      for (int half = 0; half < 2; ++half) {
        const int col = c0 + half * 8;
        const int byo = (row * 256 + col * 2) ^ ((row & 7) << 4);
        *(v8s*)(sm + 32768 + byo) = *(const v8s*)(srch + half * 8);
        *(v8s*)(sm + 49152 + byo) = *(const v8s*)(srcl + half * 8);
      }
    }
    __syncthreads();
#pragma unroll
    for (int ks = 0; ks < 4; ++ks) {
      const int kb2 = (ks * 32 + ((lane >> 4) * 8)) * 2;
      const int n = wn * 16 + (lane & 15);
      const int byoB = (n * 256 + kb2) ^ ((n & 7) << 4);
      v8s bh = *(const v8s*)(sm + 32768 + byoB);
      v8s bl = *(const v8s*)(sm + 49152 + byoB);
#pragma unroll
      for (int mi = 0; mi < 2; ++mi) {
        const int m = wm * 32 + mi * 16 + (lane & 15);
        const int byoA = (m * 256 + kb2) ^ ((m & 7) << 4);
        v8s ah = *(const v8s*)(sm + byoA);
        v8s al = *(const v8s*)(sm + 16384 + byoA);
        acc[nc][mi] = mfma16(ah, bh, acc[nc][mi]);
        acc[nc][mi] = mfma16(al, bh, acc[nc][mi]);
        acc[nc][mi] = mfma16(ah, bl, acc[nc][mi]);
        acc[nc][mi] = mfma16(al, bl, acc[nc][mi]);
      }
    }
  }
#pragma unroll
  for (int nc = 0; nc < 6; ++nc)
#pragma unroll
    for (int mi = 0; mi < 2; ++mi)
#pragma unroll
      for (int r = 0; r < 4; ++r) {
        const int m = wm * 32 + mi * 16 + ((lane >> 4) * 4) + r;
        const int n = nc * 64 + wn * 16 + (lane & 15);
        qkv[(m0 + m) * 384 + n] = acc[nc][mi][r];
      }
}

// K1g: g1 = x @ W1^T (K=256,N=128) split-bf16, fused relu+g2 dot+sigmoid+global mean (double atomic)
__global__ __launch_bounds__(512) void k1_g(const float* __restrict__ x,
                                            const short* __restrict__ g1h,
                                            const short* __restrict__ g1l,
                                            const float* __restrict__ g1_b,
                                            const float* __restrict__ g2_w,
                                            const float* __restrict__ g2_b,
                                            double* __restrict__ gsum) {
  __shared__ __align__(16) unsigned char sm[65536];
  const int tid = threadIdx.x;
  const size_t m0 = (size_t)blockIdx.x * 64;
  const int lane = tid & 63, wid = tid >> 6;
  const int wm = wid >> 2, wn = wid & 3;
  const v4f vz = {0.f, 0.f, 0.f, 0.f};
  v4f acc[2][2];
  acc[0][0] = vz; acc[0][1] = vz; acc[1][0] = vz; acc[1][1] = vz;
#pragma unroll
  for (int kc = 0; kc < 2; ++kc) {
    __syncthreads();
    { // stage A chunk (cols kc*128..+128)
      const int row = tid >> 3, c0 = (tid & 7) * 16;
      const float* src = x + (m0 + (size_t)row) * 256 + kc * 128 + c0;
#pragma unroll
      for (int half = 0; half < 2; ++half) {
        v4f f0 = *(const v4f*)(src + half * 8);
        v4f f1 = *(const v4f*)(src + half * 8 + 4);
        v8s hi, lo;
#pragma unroll
        for (int j = 0; j < 4; ++j) {
          short h0 = f2bf(f0[j]); hi[j] = h0;   lo[j]   = f2bf(f0[j] - bf2f(h0));
          short h1 = f2bf(f1[j]); hi[4+j] = h1; lo[4+j] = f2bf(f1[j] - bf2f(h1));
        }
        const int col = c0 + half * 8;
        const int byo = (row * 256 + col * 2) ^ ((row & 7) << 4);
        *(v8s*)(sm + byo) = hi;
        *(v8s*)(sm + 16384 + byo) = lo;
      }
    }
#pragma unroll
    for (int nc = 0; nc < 2; ++nc) {
      __syncthreads();
      {
        const int row = tid >> 3, c0 = (tid & 7) * 16;
        const short* srch = g1h + (size_t)(nc * 64 + row) * 256 + kc * 128 + c0;
        const short* srcl = g1l + (size_t)(nc * 64 + row) * 256 + kc * 128 + c0;
#pragma unroll
        for (int half = 0; half < 2; ++half) {
          const int col = c0 + half * 8;
          const int byo = (row * 256 + col * 2) ^ ((row & 7) << 4);
          *(v8s*)(sm + 32768 + byo) = *(const v8s*)(srch + half * 8);
          *(v8s*)(sm + 49152 + byo) = *(const v8s*)(srcl + half * 8);
        }
      }
      __syncthreads();
#pragma unroll
      for (int ks = 0; ks < 4; ++ks) {
        const int kb2 = (ks * 32 + ((lane >> 4) * 8)) * 2;
        const int n = wn * 16 + (lane & 15);
        const int byoB = (n * 256 + kb2) ^ ((n & 7) << 4);
        v8s bh = *(const v8s*)(sm + 32768 + byoB);
        v8s bl = *(const v8s*)(sm + 49152 + byoB);
#pragma unroll
        for (int mi = 0; mi < 2; ++mi) {
          const int m = wm * 32 + mi * 16 + (lane & 15);
          const int byoA = (m * 256 + kb2) ^ ((m & 7) << 4);
          v8s ah = *(const v8s*)(sm + byoA);
          v8s al = *(const v8s*)(sm + 16384 + byoA);
          acc[nc][mi] = mfma16(ah, bh, acc[nc][mi]);
          acc[nc][mi] = mfma16(al, bh, acc[nc][mi]);
          acc[nc][mi] = mfma16(ah, bl, acc[nc][mi]);
          acc[nc][mi] = mfma16(al, bl, acc[nc][mi]);
        }
      }
    }
  }
  // epilogue: per-pixel g2 dot + sigmoid + block sum -> double atomic
  __syncthreads();
  float* g2ws = (float*)sm;           // aliases dead A region
  float* ldsg = (float*)(sm + 512);
  if (tid < 128) g2ws[tid] = g2_w[tid];
  if (tid < 64) ldsg[tid] = 0.f;
  __syncthreads();
  float bias[2], g2v[2];
#pragma unroll
  for (int nc = 0; nc < 2; ++nc) {
    const int n = nc * 64 + wn * 16 + (lane & 15);
    bias[nc] = g1_b[n];
    g2v[nc] = g2ws[n];
  }
#pragma unroll
  for (int mi = 0; mi < 2; ++mi)
#pragma unroll
    for (int r = 0; r < 4; ++r) {
      float part = 0.f;
#pragma unroll
      for (int nc = 0; nc < 2; ++nc) {
        float val = acc[nc][mi][r] + bias[nc];
        val = fmaxf(val, 0.f);
        part += val * g2v[nc];
      }
      part += __shfl_xor(part, 1, 16);
      part += __shfl_xor(part, 2, 16);
      part += __shfl_xor(part, 4, 16);
      part += __shfl_xor(part, 8, 16);
      if ((lane & 15) == 0)
        atomicAdd(&ldsg[wm * 32 + mi * 16 + ((lane >> 4) * 4) + r], part);
    }
  __syncthreads();
  if (tid < 64) {
    float pre = ldsg[tid] + g2_b[0];
    float g = 1.f / (1.f + expf(-pre));
#pragma unroll
    for (int mk = 1; mk < 64; mk <<= 1) g += __shfl_xor(g, mk, 64);
    if (tid == 0) atomicAdd(gsum, (double)g);
  }
}

// K2 (redesigned): thread = (channel, row). Fused dwconv + norms + gram + v write.
// grid (256 tiles, 8 heads, 2 batch), block 256. LDS ~25.4KB.
// LDS map: haloT float[16*325] @0 (aliased by vtr short[256*24] after v-conv),
//          wsm float[144] @20800, redQ float[64] @21376, redK float[64] @21632,
//          gramW float[4*256] @21888. total 25984 B.
__global__ __launch_bounds__(256, 4) void k2_conv(const float* __restrict__ qkv,
                                                  const float* __restrict__ dw_w,
                                                  double* __restrict__ gram,
                                                  double* __restrict__ qn,
                                                  double* __restrict__ kn,
                                                  short* __restrict__ vbuf) {
  __shared__ __align__(16) unsigned char SM[25984];
  float* haloT = (float*)SM;                 // [c][325]: plane c, elem hy*18+hx
  short* vtr   = (short*)SM;                 // alias, [px][24]
  float* wsm   = (float*)(SM + 20800);       // [16][9]
  float* redQ  = (float*)(SM + 21376);       // [wave][16]
  float* redK  = (float*)(SM + 21632);
  float* gramW = (float*)(SM + 21888);       // [wave][256]

  const int tid = threadIdx.x;
  const int tile = blockIdx.x, h = blockIdx.y, b = blockIdx.z;
  const int px0 = (tile & 15) * 16, py0 = (tile >> 4) * 16;
  const int c = tid & 15, r = tid >> 4;
  const int lane = tid & 63, w4 = tid >> 6;

  auto stage = [&](int sec) {
    const int chbase = sec * 128 + h * 16;
#pragma unroll
    for (int i = 0; i < 6; ++i) {
      const int idx = tid + i * 256;
      if (idx < 1296) {
        const int p = idx >> 2, e4 = (idx & 3) * 4;
        const int row = p / 18, col = p - row * 18;
        const int gy = py0 - 1 + row, gx = px0 - 1 + col;
        v4f val = {0.f, 0.f, 0.f, 0.f};
        if (gy >= 0 && gy < 256 && gx >= 0 && gx < 256)
          val = *(const v4f*)(qkv + ((size_t)(b * 65536 + gy * 256 + gx)) * 384 + chbase + e4);
        haloT[(e4 + 0) * 325 + p] = val[0];
        haloT[(e4 + 1) * 325 + p] = val[1];
        haloT[(e4 + 2) * 325 + p] = val[2];
        haloT[(e4 + 3) * 325 + p] = val[3];
      }
    }
    if (tid < 144) wsm[tid] = dw_w[chbase * 9 + tid];
  };

  // conv for this thread's channel c, tile-row r -> 16 outputs
  auto conv16 = [&](float* o) {
#pragma unroll
    for (int j = 0; j < 16; ++j) o[j] = 0.f;
#pragma unroll
    for (int dy = 0; dy < 3; ++dy) {
      const float* rp = haloT + c * 325 + (r + dy) * 18;
      float rowb[18];
#pragma unroll
      for (int xx = 0; xx < 18; ++xx) rowb[xx] = rp[xx];
      const float w0 = wsm[c * 9 + dy * 3 + 0];
      const float w1 = wsm[c * 9 + dy * 3 + 1];
      const float w2 = wsm[c * 9 + dy * 3 + 2];
#pragma unroll
      for (int j = 0; j < 16; ++j)
        o[j] += w0 * rowb[j] + w1 * rowb[j + 1] + w2 * rowb[j + 2];
    }
  };

  float qreg[16], kreg[16];

  stage(0);
  __syncthreads();
  conv16(qreg);
  { // q-norm partial: sum over this thread's 16 px, then over the wave's 4 rows
    float s = 0.f;
#pragma unroll
    for (int j = 0; j < 16; ++j) s += qreg[j] * qreg[j];
    s += __shfl_xor(s, 16, 64);
    s += __shfl_xor(s, 32, 64);
    if (lane < 16) redQ[w4 * 16 + lane] = s;
  }
  __syncthreads();           // halo reads done
  stage(1);
  __syncthreads();
  conv16(kreg);
  {
    float s = 0.f;
#pragma unroll
    for (int j = 0; j < 16; ++j) s += kreg[j] * kreg[j];
    s += __shfl_xor(s, 16, 64);
    s += __shfl_xor(s, 32, 64);
    if (lane < 16) redK[w4 * 16 + lane] = s;
  }
  { // gram: wave covers px [64*w4, 64*w4+64); two K=32 windows, split-bf16 MFMA
    v4f acc = {0.f, 0.f, 0.f, 0.f};
    const int qt = lane >> 4;
    const bool hiHalf = (qt & 1);
#pragma unroll
    for (int f = 0; f < 2; ++f) {
      const int src = ((f * 2 + (qt >> 1)) << 4) | (lane & 15);
      v8s qh, ql, kh, kl;
#pragma unroll
      for (int j = 0; j < 8; ++j) {
        const float qa = __shfl(qreg[j], src, 64);
        const float qb = __shfl(qreg[j + 8], src, 64);
        const float ka = __shfl(kreg[j], src, 64);
        const float kb = __shfl(kreg[j + 8], src, 64);
        const float qv = hiHalf ? qb : qa;
        const float kv = hiHalf ? kb : ka;
        const short h1 = f2bf(qv); qh[j] = h1; ql[j] = f2bf(qv - bf2f(h1));
        const short h2 = f2bf(kv); kh[j] = h2; kl[j] = f2bf(kv - bf2f(h2));
      }
      acc = mfma16(qh, kh, acc);
      acc = mfma16(ql, kh, acc);
      acc = mfma16(qh, kl, acc);
      acc = mfma16(ql, kl, acc);
    }
#pragma unroll
    for (int rr = 0; rr < 4; ++rr)
      gramW[w4 * 256 + (qt * 4 + rr) * 16 + (lane & 15)] = acc[rr];
  }
  __syncthreads();           // halo reads done; redQ/redK/gramW visible
  stage(2);
  __syncthreads();
  float vv[16];
  conv16(vv);
  // finalize norms + gram (deterministic fixed-order sums, then double atomics)
  if (tid < 16) {
    const float t = redQ[tid] + redQ[16 + tid] + redQ[32 + tid] + redQ[48 + tid];
    atomicAdd(&qn[b * 128 + h * 16 + tid], (double)t);
  } else if (tid < 32) {
    const int cc = tid - 16;
    const float t = redK[cc] + redK[16 + cc] + redK[32 + cc] + redK[48 + cc];
    atomicAdd(&kn[b * 128 + h * 16 + cc], (double)t);
  }
  {
    const float g = gramW[tid] + gramW[256 + tid] + gramW[512 + tid] + gramW[768 + tid];
    atomicAdd(&gram[(size_t)(b * 8 + h) * 256 + tid], (double)g);
  }
  __syncthreads();           // all halo reads done before alias write
  { // transpose v via LDS and write pixel-major bf16
#pragma unroll
    for (int j = 0; j < 16; ++j) vtr[(r * 16 + j) * 24 + c] = f2bf(vv[j]);
  }
  __syncthreads();
  {
    const v8s o0 = *(const v8s*)(vtr + tid * 24);
    const v8s o1 = *(const v8s*)(vtr + tid * 24 + 8);
    short* dst = vbuf + ((size_t)b * 65536 + (size_t)(py0 + (tid >> 4)) * 256 + (px0 + (tid & 15))) * 128 + h * 16;
    *(v8s*)dst = o0;
    *(v8s*)(dst + 8) = o1;
  }
}

// K3a: normalize gram -> cosine attn, temperature, dyn_k top-k mask, softmax, *sum(attn1..4)
__global__ void k3a_attn(const double* __restrict__ gram, const double* __restrict__ qn,
                         const double* __restrict__ kn, const double* __restrict__ gsum,
                         const float* __restrict__ temp,
                         const float* __restrict__ a1p, const float* __restrict__ a2p,
                         const float* __restrict__ a3p, const float* __restrict__ a4p,
                         float* __restrict__ attnw) {
  const int t = threadIdx.x;  // 256 rows: (b,h,c)
  const int b = t >> 7, rem = t & 127, h = rem >> 4, c = rem & 15;
  const float qnv = fmaxf(sqrtf((float)qn[b * 128 + h * 16 + c]), 1e-12f);
  const float tv = temp[h];
  float a[16];
#pragma unroll
  for (int d = 0; d < 16; ++d) {
    const float knv = fmaxf(sqrtf((float)kn[b * 128 + h * 16 + d]), 1e-12f);
    a[d] = (float)gram[(size_t)(b * 8 + h) * 256 + c * 16 + d] / (qnv * knv) * tv;
  }
  const float dynk = floorf(16.f * (float)(gsum[0] / 131072.0));
  float mx = -INFINITY;
  bool keep[16];
#pragma unroll
  for (int d = 0; d < 16; ++d) {
    int rank = 0;
#pragma unroll
    for (int e = 0; e < 16; ++e)
      rank += ((a[e] > a[d]) || ((a[e] == a[d]) && (e < d))) ? 1 : 0;
    keep[d] = ((float)rank < dynk);
    if (keep[d]) mx = fmaxf(mx, a[d]);
  }
  float ssum = 0.f, wvv[16];
#pragma unroll
  for (int d = 0; d < 16; ++d) {
    wvv[d] = keep[d] ? expf(a[d] - mx) : 0.f;
    ssum += wvv[d];
  }
  const float satt = a1p[0] + a2p[0] + a3p[0] + a4p[0];
  const float sc = satt / ssum;
#pragma unroll
  for (int d = 0; d < 16; ++d) attnw[t * 16 + d] = wvv[d] * sc;
}

// K3b: fold attention into projection: W2[b][o][c'] (bf16)
__global__ void k3b_fold(const float* __restrict__ proj_w, const float* __restrict__ attnw,
                         short* __restrict__ W2) {
  const int o = blockIdx.x, b = blockIdx.y, cp = threadIdx.x;  // 256 threads
  float val;
  if (cp < 128) {
    const int h = cp >> 4, d = cp & 15;
    float s = 0.f;
#pragma unroll
    for (int i = 0; i < 16; ++i)
      s += proj_w[o * 256 + h * 16 + i] * attnw[((b * 8 + h) * 16 + i) * 16 + d];
    val = s;
  } else {
    val = proj_w[o * 256 + cp];
  }
  W2[(size_t)(b * 256 + o) * 256 + cp] = f2bf(val);
}

// K4: out[m][o] = [v(m) ; x2(m)] @ W2[b]^T   (M=131072, K=256, N=256) plain bf16 MFMA
__global__ __launch_bounds__(512) void k4_out(const short* __restrict__ vbuf,
                                              const float* __restrict__ x,
                                              const short* __restrict__ W2,
                                              float* __restrict__ out) {
  __shared__ __align__(16) unsigned char sm[65536]; // A [64][256] bf16 @0, B [64][256] bf16 @32768
  const int tid = threadIdx.x;
  const size_t m0 = (size_t)blockIdx.x * 64;
  const int b = (int)(m0 >> 16);
  {
    const int row = tid >> 3, c0 = (tid & 7) * 16;
    { // cols 0..127 from v (already bf16)
      const short* src = vbuf + (m0 + (size_t)row) * 128 + c0;
#pragma unroll
      for (int half = 0; half < 2; ++half) {
        const int col = c0 + half * 8;
        const int byo = (row * 512 + col * 2) ^ ((row & 7) << 4);
        *(v8s*)(sm + byo) = *(const v8s*)(src + half * 8);
      }
    }
    { // cols 128..255 from x2 (fp32 -> bf16)
      const float* src = x + (m0 + (size_t)row) * 256 + 128 + c0;
#pragma unroll
      for (int half = 0; half < 2; ++half) {
        v4f f0 = *(const v4f*)(src + half * 8);
        v4f f1 = *(const v4f*)(src + half * 8 + 4);
        v8s hv;
#pragma unroll
        for (int j = 0; j < 4; ++j) { hv[j] = f2bf(f0[j]); hv[4+j] = f2bf(f1[j]); }
        const int col = 128 + c0 + half * 8;
        const int byo = (row * 512 + col * 2) ^ ((row & 7) << 4);
        *(v8s*)(sm + byo) = hv;
      }
    }
  }
  const int lane = tid & 63, wid = tid >> 6;
  const int wm = wid >> 2, wn = wid & 3;
  for (int nc = 0; nc < 4; ++nc) {
    __syncthreads();
    { // stage B rows nc*64..+64 of W2[b]
      const int row = tid >> 3, c0 = (tid & 7) * 32;
      const short* src = W2 + ((size_t)(b * 256 + nc * 64 + row)) * 256 + c0;
#pragma unroll
      for (int q = 0; q < 4; ++q) {
        const int col = c0 + q * 8;
        const int byo = (row * 512 + col * 2) ^ ((row & 7) << 4);
        *(v8s*)(sm + 32768 + byo) = *(const v8s*)(src + q * 8);
      }
    }
    __syncthreads();
    v4f acc[2] = {{0.f,0.f,0.f,0.f},{0.f,0.f,0.f,0.f}};
#pragma unroll
    for (int ks = 0; ks < 8; ++ks) {
      const int kb2 = (ks * 32 + ((lane >> 4) * 8)) * 2;
      const int n = wn * 16 + (lane & 15);
      const int byoB = (n * 512 + kb2) ^ ((n & 7) << 4);
      const v8s bf = *(const v8s*)(sm + 32768 + byoB);
#pragma unroll
      for (int mi = 0; mi < 2; ++mi) {
        const int m = wm * 32 + mi * 16 + (lane & 15);
        const int byoA = (m * 512 + kb2) ^ ((m & 7) << 4);
        const v8s af = *(const v8s*)(sm + byoA);
        acc[mi] = mfma16(af, bf, acc[mi]);
      }
    }
#pragma unroll
    for (int mi = 0; mi < 2; ++mi)
#pragma unroll
      for (int r = 0; r < 4; ++r) {
        const int m = wm * 32 + mi * 16 + ((lane >> 4) * 4) + r;
        const int o = nc * 64 + wn * 16 + (lane & 15);
        out[(m0 + m) * 256 + o] = acc[mi][r];
      }
  }
}

extern "C" void kernel_launch(void* const* d_in, const int* in_sizes, int n_in,
                              void* d_out, int out_size, void* d_ws, size_t ws_size,
                              hipStream_t stream) {
  const float* x      = (const float*)d_in[0];
  const float* qkv_w  = (const float*)d_in[1];
  const float* dw_w   = (const float*)d_in[2];
  const float* proj_w = (const float*)d_in[3];
  const float* g1_w   = (const float*)d_in[4];
  const float* g1_b   = (const float*)d_in[5];
  const float* g2_w   = (const float*)d_in[6];
  const float* g2_b   = (const float*)d_in[7];
  const float* temp   = (const float*)d_in[8];
  const float* a1     = (const float*)d_in[9];
  const float* a2     = (const float*)d_in[10];
  const float* a3     = (const float*)d_in[11];
  const float* a4     = (const float*)d_in[12];
  float* out = (float*)d_out;
  char* ws = (char*)d_ws;

  double* gram  = (double*)(ws + OFF_GRAM);
  double* qn    = (double*)(ws + OFF_QN);
  double* kn    = (double*)(ws + OFF_KN);
  double* gsum  = (double*)(ws + OFF_GSUM);
  float*  attnw = (float*)(ws + OFF_ATTN);
  short*  wqh   = (short*)(ws + OFF_WQH);
  short*  wql   = (short*)(ws + OFF_WQL);
  short*  g1h   = (short*)(ws + OFF_G1H);
  short*  g1l   = (short*)(ws + OFF_G1L);
  short*  W2    = (short*)(ws + OFF_W2);
  float*  qkv   = (float*)(ws + OFF_QKV);
  short*  vbuf  = (short*)(ws + OFF_V);

  hipMemsetAsync(ws, 0, 40960, stream);                       // gram/qn/kn/gsum accumulators
  k0_split<<<320, 256, 0, stream>>>(qkv_w, g1_w, wqh, wql, g1h, g1l);
  k1_qkv<<<2048, 512, 0, stream>>>(x, wqh, wql, qkv);
  k1_g<<<2048, 512, 0, stream>>>(x, g1h, g1l, g1_b, g2_w, g2_b, gsum);
  k2_conv<<<dim3(256, 8, 2), 256, 0, stream>>>(qkv, dw_w, gram, qn, kn, vbuf);
  k3a_attn<<<1, 256, 0, stream>>>(gram, qn, kn, gsum, temp, a1, a2, a3, a4, attnw);
  k3b_fold<<<dim3(256, 2), 256, 0, stream>>>(proj_w, attnw, W2);
  k4_out<<<2048, 512, 0, stream>>>(vbuf, x, W2, out);
  (void)in_sizes; (void)n_in; (void)out_size; (void)ws_size;
}